// Round 11
// baseline (412.158 us; speedup 1.0000x reference)
//
#include <hip/hip_runtime.h>
#include <hip/hip_fp16.h>
#include <stdint.h>

// R18: chain shortening (all numerics-neutral; R17 bodies unchanged).
//  (a) ps1 deleted: scan_kernel computes each block's exclusive offset by
//      directly summing cnt[0..b*256) (400KB, L2-resident; worst block ~100
//      int4 loads/thread; 391 blocks fully parallel). 2 dispatches -> 1.
//  (b) agg-zero (51.2 MB) moved from zero_probe into prep as a 4th block
//      section -- prep is 2 dispatches before edge so dirty lines flush
//      during scan+sl (avoids R14's adjacent-dispatch drain regression).
//      zero_probe now clears only cnt (400 KB).
// 7 -> 6 dispatches.

#define N_NODES 100000
#define N_GRAPH 5000
#define N_EDGE  1000000
#define H 128
#define NBLK 391   // ceil(N_NODES/256)

typedef unsigned short u16;
typedef __attribute__((ext_vector_type(8))) short short8;
typedef __attribute__((ext_vector_type(4))) float floatx4;

__device__ inline float b2f(u16 x) {
    unsigned u = ((unsigned)x) << 16;
    return __uint_as_float(u);
}
__device__ inline u16 f2b(float f) {
    unsigned u = __float_as_uint(f);
    unsigned r = (u + 0x7FFFu + ((u >> 16) & 1u)) >> 16;  // RNE
    return (u16)r;
}
__device__ inline unsigned cvt_pk_bf16(float lo, float hi) {
    unsigned r;
    asm("v_cvt_pk_bf16_f32 %0, %1, %2" : "=v"(r) : "v"(lo), "v"(hi));
    return r;
}
__device__ inline float silu_f(float x) {
    float e = __builtin_amdgcn_exp2f(x * -1.442695040888963f);
    return x * __builtin_amdgcn_rcpf(1.f + e);
}
__device__ inline float get_bf(const uint4& v, int j) {
    unsigned w = ((const unsigned*)&v)[j >> 1];
    return b2f((u16)(w >> (16 * (j & 1))));
}
__device__ inline u16 f2h(float f) {       // f32 -> f16 bits (RNE, 1 op)
    return __half_as_ushort(__float2half(f));
}
__device__ inline __half2 h2u(unsigned w) {
    __half2 r; __builtin_memcpy(&r, &w, 4); return r;
}

// ---------------- zero cnt (400 KB) + dtype probe ----------------
__global__ void zero_probe_kernel(uint4* __restrict__ zp, long n16,
                                  const unsigned* __restrict__ nf_raw, int* __restrict__ flag) {
    long i = (long)blockIdx.x * blockDim.x + threadIdx.x;
    long stride = (long)gridDim.x * blockDim.x;
    uint4 z = make_uint4(0, 0, 0, 0);
    for (; i < n16; i += stride) zp[i] = z;
    if (blockIdx.x == 0) {
        __shared__ int cnt_s;
        if (threadIdx.x == 0) cnt_s = 0;
        __syncthreads();
        unsigned u = nf_raw[threadIdx.x];
        unsigned e2 = (u >> 7) & 0xFF;
        atomicAdd(&cnt_s, (e2 >= 90 && e2 <= 160) ? 1 : 0);
        __syncthreads();
        if (threadIdx.x == 0) *flag = (cnt_s >= 128) ? 1 : 0;
    }
}

// ---------------- fused prep: packall + lg + cnt + agg-zero ----------------
#define PREP_PACK_BLK 48
#define PREP_LG_BLK   1250
#define PREP_CNT_BLK  3907
#define PREP_ZERO_BLK 3200   // 3200*1024 uint4 >= 3.2M uint4 (51.2 MB agg)
#define PREP_TOTAL    (PREP_PACK_BLK + PREP_LG_BLK + PREP_CNT_BLK + PREP_ZERO_BLK)
#define AGG_U4        ((long)N_NODES * H / 4)   // 3.2M uint4

__global__ void prep_kernel(const void* __restrict__ W1e, const void* __restrict__ W2e,
                            const void* __restrict__ W1n, const void* __restrict__ W2n,
                            u16* __restrict__ W1tp, u16* __restrict__ W1mp, u16* __restrict__ W2p,
                            u16* __restrict__ W1np, u16* __restrict__ W2np,
                            const void* __restrict__ lat, const void* __restrict__ b1e,
                            u16* __restrict__ LGb,
                            const int* __restrict__ ei, int* __restrict__ cnt,
                            uint4* __restrict__ aggz,
                            const int* __restrict__ flagp) {
    int blk = blockIdx.x;
    if (blk < PREP_PACK_BLK) {
        // ---- packall: 5 weight matrices -> MFMA B-fragment layout (bf16) ----
        int bf = *flagp;
        const void* W; u16* out; int k0, Ktot, base;
        if (blk < 8)       { W = W1e; out = W1tp; k0 = 0;   Ktot = 268; base = 0; }
        else if (blk < 16) { W = W1e; out = W1mp; k0 = 128; Ktot = 268; base = 8; }
        else if (blk < 24) { W = W2e; out = W2p;  k0 = 0;   Ktot = 128; base = 16; }
        else if (blk < 40) { W = W1n; out = W1np; k0 = 0;   Ktot = 256; base = 24; }
        else               { W = W2n; out = W2np; k0 = 0;   Ktot = 128; base = 40; }
        int t = (blk - base) * 256 + threadIdx.x;
        int lane = t & 63, nt = (t >> 6) & 7, kt = t >> 9;
        int n = nt * 16 + (lane & 15);
        int kbase = k0 + kt * 32 + ((lane >> 4) << 3);
        u16 vals[8];
        #pragma unroll
        for (int j = 0; j < 8; j++) {
            int k = kbase + j;
            if (k >= Ktot) vals[j] = 0;
            else if (bf) vals[j] = ((const u16*)W)[(size_t)k * H + n];
            else vals[j] = f2b(((const float*)W)[(size_t)k * H + n]);
        }
        uint4 tmp;
        __builtin_memcpy(&tmp, vals, 16);
        *(uint4*)(out + (size_t)t * 8) = tmp;
    } else if (blk < PREP_PACK_BLK + PREP_LG_BLK) {
        // ---- lg: LG[g][c] = b1e[c] + sum_ij ltl(g)_ij * W1e[256+ij][c]  (f16 out) ----
        int bf = *flagp;
        int t = (blk - PREP_PACK_BLK) * 256 + threadIdx.x;
        if (t >= N_GRAPH * 64) return;
        int g = t >> 6, cp = (t & 63) * 2;
        float L[9];
        #pragma unroll
        for (int k = 0; k < 9; k++)
            L[k] = bf ? b2f(((const u16*)lat)[g * 9 + k]) : ((const float*)lat)[g * 9 + k];
        float a0 = bf ? b2f(((const u16*)b1e)[cp])     : ((const float*)b1e)[cp];
        float a1 = bf ? b2f(((const u16*)b1e)[cp + 1]) : ((const float*)b1e)[cp + 1];
        #pragma unroll
        for (int i = 0; i < 3; i++) {
            #pragma unroll
            for (int j = 0; j < 3; j++) {
                float lt = L[i*3] * L[j*3] + L[i*3+1] * L[j*3+1] + L[i*3+2] * L[j*3+2];
                int r = 256 + i * 3 + j;
                float w0 = bf ? b2f(((const u16*)W1e)[(size_t)r * H + cp])     : ((const float*)W1e)[(size_t)r * H + cp];
                float w1 = bf ? b2f(((const u16*)W1e)[(size_t)r * H + cp + 1]) : ((const float*)W1e)[(size_t)r * H + cp + 1];
                a0 += lt * w0;
                a1 += lt * w1;
            }
        }
        LGb[(size_t)g * H + cp]     = f2h(a0);
        LGb[(size_t)g * H + cp + 1] = f2h(a1);
    } else if (blk < PREP_PACK_BLK + PREP_LG_BLK + PREP_CNT_BLK) {
        // ---- cnt: degree counts over edge_index[0] ----
        int e = (blk - PREP_PACK_BLK - PREP_LG_BLK) * 256 + threadIdx.x;
        if (e < N_EDGE) atomicAdd(&cnt[ei[e]], 1);
    } else {
        // ---- agg zero: 51.2 MB, flushed during scan+sl (2 dispatches pre-edge) ----
        long z = blk - (PREP_PACK_BLK + PREP_LG_BLK + PREP_CNT_BLK);
        long i0 = z * 1024 + threadIdx.x;
        uint4 zero = make_uint4(0, 0, 0, 0);
        #pragma unroll
        for (int k = 0; k < 4; k++) {
            long i = i0 + k * 256;
            if (i < AGG_U4) aggz[i] = zero;
        }
    }
}

// ---------------- single-dispatch scan: per-block direct prefix over cnt ----------------
__global__ void scan_kernel(const int* __restrict__ cnt, int* __restrict__ starts) {
    __shared__ int s[256];
    __shared__ int sOff;
    int b = blockIdx.x;
    int t = threadIdx.x;
    // exclusive offset = sum cnt[0 .. b*256)  (L2-resident 400 KB, int4 loads)
    long lim4 = (long)b * 64;                  // (b*256)/4, exact
    const int4* c4 = (const int4*)cnt;
    int acc = 0;
    for (long i = t; i < lim4; i += 256) {
        int4 v = c4[i];
        acc += v.x + v.y + v.z + v.w;
    }
    s[t] = acc;
    __syncthreads();
    for (int off = 128; off >= 1; off >>= 1) {
        if (t < off) s[t] += s[t + off];
        __syncthreads();
    }
    if (t == 0) sOff = s[0];
    __syncthreads();
    // local inclusive scan of cnt within this block
    int i = b * 256 + t;
    int v = (i < N_NODES) ? cnt[i] : 0;
    s[t] = v;
    __syncthreads();
    for (int off = 1; off < 256; off <<= 1) {
        int add = (t >= off) ? s[t - off] : 0;
        __syncthreads();
        s[t] += add;
        __syncthreads();
    }
    if (i < N_NODES) starts[i] = sOff + s[t] - v;
}

// ---------------- fused scatter + lnuv (independent producers for edge) ----------------
#define UVP 136
#define SC_BLK 3907                 // ceil(N_EDGE/256)
#define LN_BLK 1563                 // ceil(N_NODES/64)
#define SL_TOTAL (SC_BLK + LN_BLK)  // 5470

__global__ __launch_bounds__(256, 3) void sl_kernel(
    // scatter args
    const int* __restrict__ ei, const int* __restrict__ e2g,
    const void* __restrict__ fd, int* __restrict__ starts, int4* __restrict__ rec,
    // lnuv args
    const void* __restrict__ nf, const void* __restrict__ lng, const void* __restrict__ lnb,
    const u16* __restrict__ Wtp, const u16* __restrict__ Wmp,
    u16* __restrict__ U, u16* __restrict__ V,
    const int* __restrict__ flagp) {
    __shared__ __align__(16) u16 sA[64 * UVP];
    int blk = blockIdx.x;
    int tid = threadIdx.x;
    int bf = *flagp;

    // Bresenham role split: lnuv iff floor((blk+1)*LN/TOT) > floor(blk*LN/TOT)
    int li = (int)(((long)blk * LN_BLK) / SL_TOTAL);
    int isLn = (int)(((long)(blk + 1) * LN_BLK) / SL_TOTAL) > li;

    if (!isLn) {
        // ================= scatter body =================
        int si = blk - li;
        int e = si * 256 + tid;
        if (e >= N_EDGE) return;
        int s = ei[e];
        int pos = atomicAdd(&starts[s], 1);
        float f0, f1, f2v;
        if (bf) {
            const u16* f = (const u16*)fd + (size_t)e * 3;
            f0 = b2f(f[0]); f1 = b2f(f[1]); f2v = b2f(f[2]);
        } else {
            const float* f = (const float*)fd + (size_t)e * 3;
            f0 = f[0]; f1 = f[1]; f2v = f[2];
        }
        int fd01 = (int)((unsigned)f2h(f0) | ((unsigned)f2h(f1) << 16));
        int gz = (int)((unsigned)e2g[e] | ((unsigned)f2h(f2v) << 16));
        rec[pos] = make_int4(s, ei[N_EDGE + e], gz, fd01);
        return;
    }

    // ================= lnuv body =================
    int lane = tid & 63, w = tid >> 6;
    int r0 = li * 64;

    {
        int row = tid >> 2, part = tid & 3;
        int gr = r0 + row;
        int grc = (gr < N_NODES) ? gr : N_NODES - 1;
        float x[32];
        if (bf) {
            const u16* p = (const u16*)nf + (size_t)grc * H + part * 32;
            #pragma unroll
            for (int j8 = 0; j8 < 4; j8++) {
                uint4 v = *(const uint4*)(p + j8 * 8);
                #pragma unroll
                for (int j = 0; j < 8; j++) x[j8 * 8 + j] = get_bf(v, j);
            }
        } else {
            const float* p = (const float*)nf + (size_t)grc * H + part * 32;
            #pragma unroll
            for (int j4 = 0; j4 < 8; j4++) {
                float4 v = *(const float4*)(p + j4 * 4);
                x[j4*4] = v.x; x[j4*4+1] = v.y; x[j4*4+2] = v.z; x[j4*4+3] = v.w;
            }
        }
        float s1 = 0.f, s2 = 0.f;
        #pragma unroll
        for (int j = 0; j < 32; j++) { s1 += x[j]; s2 += x[j] * x[j]; }
        s1 += __shfl_xor(s1, 1, 64); s2 += __shfl_xor(s2, 1, 64);
        s1 += __shfl_xor(s1, 2, 64); s2 += __shfl_xor(s2, 2, 64);
        float mu = s1 * (1.0f / H);
        float var = s2 * (1.0f / H) - mu * mu;
        float rs = rsqrtf(var + 1e-5f);
        unsigned pk[16];
        if (bf) {
            const u16* gp = (const u16*)lng + part * 32;
            const u16* bp = (const u16*)lnb + part * 32;
            #pragma unroll
            for (int j8 = 0; j8 < 4; j8++) {
                uint4 gv = *(const uint4*)(gp + j8 * 8);
                uint4 bv = *(const uint4*)(bp + j8 * 8);
                #pragma unroll
                for (int j2 = 0; j2 < 4; j2++) {
                    int j = j8 * 8 + j2 * 2;
                    float y0 = (x[j] - mu) * rs * get_bf(gv, j2*2)     + get_bf(bv, j2*2);
                    float y1 = (x[j+1] - mu) * rs * get_bf(gv, j2*2+1) + get_bf(bv, j2*2+1);
                    pk[j >> 1] = cvt_pk_bf16(y0, y1);
                }
            }
        } else {
            const float* gp = (const float*)lng + part * 32;
            const float* bp = (const float*)lnb + part * 32;
            #pragma unroll
            for (int j4 = 0; j4 < 8; j4++) {
                float4 gv = *(const float4*)(gp + j4 * 4);
                float4 bv = *(const float4*)(bp + j4 * 4);
                int j = j4 * 4;
                float y0 = (x[j]   - mu) * rs * gv.x + bv.x;
                float y1 = (x[j+1] - mu) * rs * gv.y + bv.y;
                float y2 = (x[j+2] - mu) * rs * gv.z + bv.z;
                float y3 = (x[j+3] - mu) * rs * gv.w + bv.w;
                pk[j >> 1]       = cvt_pk_bf16(y0, y1);
                pk[(j >> 1) + 1] = cvt_pk_bf16(y2, y3);
            }
        }
        uint4* d = (uint4*)&sA[row * UVP + part * 32];
        #pragma unroll
        for (int j4 = 0; j4 < 4; j4++)
            d[j4] = make_uint4(pk[j4*4], pk[j4*4+1], pk[j4*4+2], pk[j4*4+3]);
    }
    __syncthreads();

    const short8* Wt = (const short8*)Wtp;
    const short8* Wm = (const short8*)Wmp;
    int q8 = (lane >> 4) * 8;
    int mrow = lane & 15;
    int q = lane >> 4;

    floatx4 aU[4][2], aV[4][2];
    #pragma unroll
    for (int mt = 0; mt < 4; mt++) {
        aU[mt][0] = (floatx4){0,0,0,0}; aU[mt][1] = (floatx4){0,0,0,0};
        aV[mt][0] = (floatx4){0,0,0,0}; aV[mt][1] = (floatx4){0,0,0,0};
    }
    #pragma unroll
    for (int kt = 0; kt < 4; kt++) {
        short8 bu0 = Wt[(kt * 8 + 2 * w) * 64 + lane];
        short8 bu1 = Wt[(kt * 8 + 2 * w + 1) * 64 + lane];
        short8 bv0 = Wm[(kt * 8 + 2 * w) * 64 + lane];
        short8 bv1 = Wm[(kt * 8 + 2 * w + 1) * 64 + lane];
        #pragma unroll
        for (int mt = 0; mt < 4; mt++) {
            short8 a = *(const short8*)(&sA[(mt * 16 + mrow) * UVP + kt * 32 + q8]);
            aU[mt][0] = __builtin_amdgcn_mfma_f32_16x16x32_bf16(a, bu0, aU[mt][0], 0, 0, 0);
            aU[mt][1] = __builtin_amdgcn_mfma_f32_16x16x32_bf16(a, bu1, aU[mt][1], 0, 0, 0);
            aV[mt][0] = __builtin_amdgcn_mfma_f32_16x16x32_bf16(a, bv0, aV[mt][0], 0, 0, 0);
            aV[mt][1] = __builtin_amdgcn_mfma_f32_16x16x32_bf16(a, bv1, aV[mt][1], 0, 0, 0);
        }
    }
    __syncthreads();   // sA free; LDS-bounce U then V for vector stores (f16)

    #pragma unroll
    for (int mt = 0; mt < 4; mt++)
        #pragma unroll
        for (int nt = 0; nt < 2; nt++) {
            int n = w * 32 + nt * 16 + mrow;
            #pragma unroll
            for (int r = 0; r < 4; r++)
                sA[(mt * 16 + q * 4 + r) * UVP + n] = f2h(aU[mt][nt][r]);
        }
    __syncthreads();
    for (int i = tid; i < 1024; i += 256) {
        int row = i >> 4, c = i & 15;
        int gr = r0 + row;
        if (gr < N_NODES)
            *(uint4*)(U + (size_t)gr * H + c * 8) = *(const uint4*)(&sA[row * UVP + c * 8]);
    }
    __syncthreads();
    #pragma unroll
    for (int mt = 0; mt < 4; mt++)
        #pragma unroll
        for (int nt = 0; nt < 2; nt++) {
            int n = w * 32 + nt * 16 + mrow;
            #pragma unroll
            for (int r = 0; r < 4; r++)
                sA[(mt * 16 + q * 4 + r) * UVP + n] = f2h(aV[mt][nt][r]);
        }
    __syncthreads();
    for (int i = tid; i < 1024; i += 256) {
        int row = i >> 4, c = i & 15;
        int gr = r0 + row;
        if (gr < N_NODES)
            *(uint4*)(V + (size_t)gr * H + c * 8) = *(const uint4*)(&sA[row * UVP + c * 8]);
    }
}

// ---------------- fused edge (src-sorted): packed-f16 gather + silu -> layer2 GEMM -> segmented reduce ----------------
#define PP 136   // bf16 stage-1 stride (u16 units)
#define PF2 132  // f32 chunked-epilogue stride (floats); 132%32=4 -> 2-way banks

__global__ __launch_bounds__(256, 8) void edge_kernel(
    const u16* __restrict__ U, const u16* __restrict__ V, const u16* __restrict__ LGb,
    const int4* __restrict__ rec,
    const void* __restrict__ W1e,
    const u16* __restrict__ W2p, const void* __restrict__ bias2,
    float* __restrict__ agg, const int* __restrict__ flagp) {
    __shared__ __align__(16) u16 sP[64 * PP];
    float* sPf = (float*)sP;
    __shared__ int sSrc[64], sDst[64], sG[64];
    __shared__ unsigned sFdU[192];   // f16x2 splats: {f0,f0},{f1,f1},{f2,f2} per row
    __shared__ float sB2[128];

    int bf = *flagp;
    int tid = threadIdx.x;
    int lane = tid & 63, w = tid >> 6;
    int e0 = blockIdx.x * 64;

    if (tid < 64) {
        int4 r = rec[e0 + tid];
        sSrc[tid] = r.x; sDst[tid] = r.y;
        sG[tid] = (int)((unsigned)r.z & 0xFFFFu);
        unsigned wv = (unsigned)r.w;
        unsigned a = wv & 0xFFFFu;
        unsigned b = wv >> 16;
        unsigned c = ((unsigned)r.z) >> 16;
        sFdU[tid * 3 + 0] = a | (a << 16);
        sFdU[tid * 3 + 1] = b | (b << 16);
        sFdU[tid * 3 + 2] = c | (c << 16);
    }
    if (tid < 128) sB2[tid] = bf ? b2f(((const u16*)bias2)[tid]) : ((const float*)bias2)[tid];

    // Wfd = W1e rows 265..267, cols c8..c8+7 (fixed per thread) -> f16x2 pairs
    int c8 = (tid & 15) * 8;
    __half2 wfh[3][4];
    if (bf) {
        #pragma unroll
        for (int k = 0; k < 3; k++) {
            uint4 wv = *(const uint4*)((const u16*)W1e + (size_t)(265 + k) * H + c8);
            #pragma unroll
            for (int jj = 0; jj < 4; jj++)
                wfh[k][jj] = __floats2half2_rn(get_bf(wv, 2 * jj), get_bf(wv, 2 * jj + 1));
        }
    } else {
        #pragma unroll
        for (int k = 0; k < 3; k++) {
            const float* wr = (const float*)W1e + (size_t)(265 + k) * H + c8;
            float4 a4 = *(const float4*)wr;
            float4 b4 = *(const float4*)(wr + 4);
            wfh[k][0] = __floats2half2_rn(a4.x, a4.y);
            wfh[k][1] = __floats2half2_rn(a4.z, a4.w);
            wfh[k][2] = __floats2half2_rn(b4.x, b4.y);
            wfh[k][3] = __floats2half2_rn(b4.z, b4.w);
        }
    }
    __syncthreads();

    // gather: packed f16 adds/fmas -> f32 silu -> bf16 A-tile in sP
    for (int i = tid; i < 1024; i += 256) {
        int row = i >> 4;
        int s = sSrc[row], d = sDst[row], g = sG[row];
        uint4 uu = *(const uint4*)(U + (size_t)s * H + c8);
        uint4 vv = *(const uint4*)(V + (size_t)d * H + c8);
        uint4 gg = *(const uint4*)(LGb + (size_t)g * H + c8);
        __half2 f0h = h2u(sFdU[row * 3 + 0]);
        __half2 f1h = h2u(sFdU[row * 3 + 1]);
        __half2 f2h = h2u(sFdU[row * 3 + 2]);
        float y[8];
        #pragma unroll
        for (int jj = 0; jj < 4; jj++) {
            __half2 z = __hadd2(h2u(((const unsigned*)&uu)[jj]), h2u(((const unsigned*)&vv)[jj]));
            z = __hadd2(z, h2u(((const unsigned*)&gg)[jj]));
            z = __hfma2(f0h, wfh[0][jj], z);
            z = __hfma2(f1h, wfh[1][jj], z);
            z = __hfma2(f2h, wfh[2][jj], z);
            float2 zf = __half22float2(z);
            y[2 * jj]     = silu_f(zf.x);
            y[2 * jj + 1] = silu_f(zf.y);
        }
        uint4 packed = make_uint4(cvt_pk_bf16(y[0], y[1]), cvt_pk_bf16(y[2], y[3]),
                                  cvt_pk_bf16(y[4], y[5]), cvt_pk_bf16(y[6], y[7]));
        *(uint4*)(&sP[row * PP + c8]) = packed;
    }
    __syncthreads();

    const short8* W2v = (const short8*)W2p;
    int q8 = (lane >> 4) * 8;
    int mrow = lane & 15;
    int q = lane >> 4;

    // layer 2: [64,128] @ [128,128]
    floatx4 acc2[4][2];
    #pragma unroll
    for (int mt = 0; mt < 4; mt++) {
        acc2[mt][0] = (floatx4){0,0,0,0};
        acc2[mt][1] = (floatx4){0,0,0,0};
    }
    #pragma unroll
    for (int kt = 0; kt < 4; kt++) {
        short8 bf0 = W2v[(kt * 8 + 2 * w) * 64 + lane];
        short8 bf1 = W2v[(kt * 8 + 2 * w + 1) * 64 + lane];
        #pragma unroll
        for (int mt = 0; mt < 4; mt++) {
            short8 a = *(const short8*)(&sP[(mt * 16 + mrow) * PP + kt * 32 + q8]);
            acc2[mt][0] = __builtin_amdgcn_mfma_f32_16x16x32_bf16(a, bf0, acc2[mt][0], 0, 0, 0);
            acc2[mt][1] = __builtin_amdgcn_mfma_f32_16x16x32_bf16(a, bf1, acc2[mt][1], 0, 0, 0);
        }
    }
    __syncthreads();   // all sP A-frag reads done; safe to overwrite with f32 chunk

    // bias + silu -> f32 LDS in two 32-row chunks (mt 0,1 then mt 2,3),
    // each followed by the segmented reduce over that chunk.
    int col = tid & 127;
    int sub = tid >> 7;
    #pragma unroll
    for (int ch = 0; ch < 2; ch++) {
        if (ch) __syncthreads();     // chunk-0 reduce reads done before overwrite
        #pragma unroll
        for (int mt2 = 0; mt2 < 2; mt2++) {
            int mt = ch * 2 + mt2;
            #pragma unroll
            for (int nt = 0; nt < 2; nt++) {
                int n = w * 32 + nt * 16 + mrow;
                float bias = sB2[n];
                #pragma unroll
                for (int r = 0; r < 4; r++) {
                    int rl = mt2 * 16 + q * 4 + r;   // chunk-local row
                    sPf[rl * PF2 + n] = silu_f(acc2[mt][nt][r] + bias);
                }
            }
        }
        __syncthreads();
        // segmented reduce: 16-row window per thread-half, one atomic per run
        int rbase = sub * 16;                 // chunk-local
        int growb = ch * 32 + rbase;          // block-local (for sSrc)
        float acc = 0.f;
        int cur = sSrc[growb];
        #pragma unroll 4
        for (int rr = 0; rr < 16; rr++) {
            int s = sSrc[growb + rr];
            if (s != cur) {
                atomicAdd(&agg[(size_t)cur * H + col], acc);
                acc = 0.f;
                cur = s;
            }
            acc += sPf[(rbase + rr) * PF2 + col];
        }
        atomicAdd(&agg[(size_t)cur * H + col], acc);
    }
}

// ---------------- node MLP + residual (LN recomputed from nf) ----------------
#define NKP 264

__global__ __launch_bounds__(256, 4) void node_kernel(
    const float* __restrict__ agg, const int* __restrict__ cnt,
    const void* __restrict__ nf,
    const void* __restrict__ lng, const void* __restrict__ lnb,
    const u16* __restrict__ W1p, const u16* __restrict__ W2p,
    const void* __restrict__ bias1, const void* __restrict__ bias2,
    void* __restrict__ out, const int* __restrict__ flagp) {
    __shared__ __align__(16) u16 sU[64 * NKP];
    __shared__ float sB1[128], sB2[128];
    u16* sA = sU;
    u16* sP = sU;

    int bf = *flagp;
    int tid = threadIdx.x;
    int lane = tid & 63, w = tid >> 6;
    int r0 = blockIdx.x * 64;

    if (tid < 128) sB1[tid] = bf ? b2f(((const u16*)bias1)[tid]) : ((const float*)bias1)[tid];
    else sB2[tid - 128] = bf ? b2f(((const u16*)bias2)[tid - 128]) : ((const float*)bias2)[tid - 128];

    // ---- LN stage (identical math to lnuv -> bit-identical bf16): cols 0..127 ----
    {
        int row = tid >> 2, part = tid & 3;
        int gr = r0 + row;
        int grc = (gr < N_NODES) ? gr : N_NODES - 1;
        float x[32];
        if (bf) {
            const u16* p = (const u16*)nf + (size_t)grc * H + part * 32;
            #pragma unroll
            for (int j8 = 0; j8 < 4; j8++) {
                uint4 v = *(const uint4*)(p + j8 * 8);
                #pragma unroll
                for (int j = 0; j < 8; j++) x[j8 * 8 + j] = get_bf(v, j);
            }
        } else {
            const float* p = (const float*)nf + (size_t)grc * H + part * 32;
            #pragma unroll
            for (int j4 = 0; j4 < 8; j4++) {
                float4 v = *(const float4*)(p + j4 * 4);
                x[j4*4] = v.x; x[j4*4+1] = v.y; x[j4*4+2] = v.z; x[j4*4+3] = v.w;
            }
        }
        float s1 = 0.f, s2 = 0.f;
        #pragma unroll
        for (int j = 0; j < 32; j++) { s1 += x[j]; s2 += x[j] * x[j]; }
        s1 += __shfl_xor(s1, 1, 64); s2 += __shfl_xor(s2, 1, 64);
        s1 += __shfl_xor(s1, 2, 64); s2 += __shfl_xor(s2, 2, 64);
        float mu = s1 * (1.0f / H);
        float var = s2 * (1.0f / H) - mu * mu;
        float rs = rsqrtf(var + 1e-5f);
        unsigned pk[16];
        if (bf) {
            const u16* gp = (const u16*)lng + part * 32;
            const u16* bp = (const u16*)lnb + part * 32;
            #pragma unroll
            for (int j8 = 0; j8 < 4; j8++) {
                uint4 gv = *(const uint4*)(gp + j8 * 8);
                uint4 bv = *(const uint4*)(bp + j8 * 8);
                #pragma unroll
                for (int j2 = 0; j2 < 4; j2++) {
                    int j = j8 * 8 + j2 * 2;
                    float y0 = (x[j] - mu) * rs * get_bf(gv, j2*2)     + get_bf(bv, j2*2);
                    float y1 = (x[j+1] - mu) * rs * get_bf(gv, j2*2+1) + get_bf(bv, j2*2+1);
                    pk[j >> 1] = cvt_pk_bf16(y0, y1);
                }
            }
        } else {
            const float* gp = (const float*)lng + part * 32;
            const float* bp = (const float*)lnb + part * 32;
            #pragma unroll
            for (int j4 = 0; j4 < 8; j4++) {
                float4 gv = *(const float4*)(gp + j4 * 4);
                float4 bv = *(const float4*)(bp + j4 * 4);
                int j = j4 * 4;
                float y0 = (x[j]   - mu) * rs * gv.x + bv.x;
                float y1 = (x[j+1] - mu) * rs * gv.y + bv.y;
                float y2 = (x[j+2] - mu) * rs * gv.z + bv.z;
                float y3 = (x[j+3] - mu) * rs * gv.w + bv.w;
                pk[j >> 1]       = cvt_pk_bf16(y0, y1);
                pk[(j >> 1) + 1] = cvt_pk_bf16(y2, y3);
            }
        }
        uint4* d = (uint4*)&sA[row * NKP + part * 32];
        #pragma unroll
        for (int j4 = 0; j4 < 4; j4++)
            d[j4] = make_uint4(pk[j4*4], pk[j4*4+1], pk[j4*4+2], pk[j4*4+3]);
    }

    // stage agg/cnt rows (cols 128..255), fp32 -> bf16 with packed converts
    for (int i = tid; i < 1024; i += 256) {
        int row = i >> 4, c = i & 15;
        int gr = r0 + row; if (gr >= N_NODES) gr = N_NODES - 1;
        int cn = cnt[gr];
        float sc = 1.0f / (float)(cn > 0 ? cn : 1);
        const float* ap = agg + (size_t)gr * H + c * 8;
        float4 a4 = *(const float4*)ap;
        float4 b4 = *(const float4*)(ap + 4);
        uint4 packed = make_uint4(cvt_pk_bf16(a4.x * sc, a4.y * sc), cvt_pk_bf16(a4.z * sc, a4.w * sc),
                                  cvt_pk_bf16(b4.x * sc, b4.y * sc), cvt_pk_bf16(b4.z * sc, b4.w * sc));
        *(uint4*)(&sA[row * NKP + 128 + c * 8]) = packed;
    }
    __syncthreads();

    const short8* W1v = (const short8*)W1p;
    const short8* W2v = (const short8*)W2p;
    int q8 = (lane >> 4) * 8;
    int mrow = lane & 15;
    int q = lane >> 4;

    floatx4 acc[4][2];
    #pragma unroll
    for (int mt = 0; mt < 4; mt++) {
        acc[mt][0] = (floatx4){0,0,0,0};
        acc[mt][1] = (floatx4){0,0,0,0};
    }
    #pragma unroll
    for (int kt = 0; kt < 8; kt++) {
        short8 bf0 = W1v[(kt * 8 + 2 * w) * 64 + lane];
        short8 bf1 = W1v[(kt * 8 + 2 * w + 1) * 64 + lane];
        #pragma unroll
        for (int mt = 0; mt < 4; mt++) {
            short8 a = *(const short8*)(&sA[(mt * 16 + mrow) * NKP + kt * 32 + q8]);
            acc[mt][0] = __builtin_amdgcn_mfma_f32_16x16x32_bf16(a, bf0, acc[mt][0], 0, 0, 0);
            acc[mt][1] = __builtin_amdgcn_mfma_f32_16x16x32_bf16(a, bf1, acc[mt][1], 0, 0, 0);
        }
    }
    __syncthreads();

    #pragma unroll
    for (int mt = 0; mt < 4; mt++) {
        #pragma unroll
        for (int nt = 0; nt < 2; nt++) {
            int n = w * 32 + nt * 16 + mrow;
            float bias = sB1[n];
            #pragma unroll
            for (int r = 0; r < 4; r++) {
                int row = mt * 16 + q * 4 + r;
                sP[row * PP + n] = f2b(silu_f(acc[mt][nt][r] + bias));
            }
        }
    }
    __syncthreads();

    floatx4 acc2[4][2];
    #pragma unroll
    for (int mt = 0; mt < 4; mt++) {
        acc2[mt][0] = (floatx4){0,0,0,0};
        acc2[mt][1] = (floatx4){0,0,0,0};
    }
    #pragma unroll
    for (int kt = 0; kt < 4; kt++) {
        short8 bf0 = W2v[(kt * 8 + 2 * w) * 64 + lane];
        short8 bf1 = W2v[(kt * 8 + 2 * w + 1) * 64 + lane];
        #pragma unroll
        for (int mt = 0; mt < 4; mt++) {
            short8 a = *(const short8*)(&sP[(mt * 16 + mrow) * PP + kt * 32 + q8]);
            acc2[mt][0] = __builtin_amdgcn_mfma_f32_16x16x32_bf16(a, bf0, acc2[mt][0], 0, 0, 0);
            acc2[mt][1] = __builtin_amdgcn_mfma_f32_16x16x32_bf16(a, bf1, acc2[mt][1], 0, 0, 0);
        }
    }
    __syncthreads();   // sP free again; LDS-bounce for vector out stores

    #pragma unroll
    for (int mt = 0; mt < 4; mt++) {
        #pragma unroll
        for (int nt = 0; nt < 2; nt++) {
            int n = w * 32 + nt * 16 + mrow;
            float bias = sB2[n];
            #pragma unroll
            for (int r = 0; r < 4; r++) {
                int row = mt * 16 + q * 4 + r;
                sP[row * PP + n] = f2b(silu_f(acc2[mt][nt][r] + bias));
            }
        }
    }
    __syncthreads();

    // vectorized residual add + store
    for (int i = tid; i < 1024; i += 256) {
        int row = i >> 4, c = i & 15;
        int gr = r0 + row;
        if (gr >= N_NODES) continue;
        uint4 sv = *(const uint4*)(&sP[row * PP + c * 8]);
        size_t idx = (size_t)gr * H + c * 8;
        if (bf) {
            uint4 nv = *(const uint4*)((const u16*)nf + idx);
            float o[8];
            #pragma unroll
            for (int j = 0; j < 8; j++) o[j] = get_bf(nv, j) + get_bf(sv, j);
            uint4 packed = make_uint4(cvt_pk_bf16(o[0], o[1]), cvt_pk_bf16(o[2], o[3]),
                                      cvt_pk_bf16(o[4], o[5]), cvt_pk_bf16(o[6], o[7]));
            *(uint4*)((u16*)out + idx) = packed;
        } else {
            const float* np = (const float*)nf + idx;
            float4 a4 = *(const float4*)np;
            float4 b4 = *(const float4*)(np + 4);
            a4.x += get_bf(sv, 0); a4.y += get_bf(sv, 1); a4.z += get_bf(sv, 2); a4.w += get_bf(sv, 3);
            b4.x += get_bf(sv, 4); b4.y += get_bf(sv, 5); b4.z += get_bf(sv, 6); b4.w += get_bf(sv, 7);
            float* op = (float*)out + idx;
            *(float4*)op = a4;
            *(float4*)(op + 4) = b4;
        }
    }
}

extern "C" void kernel_launch(void* const* d_in, const int* in_sizes, int n_in,
                              void* d_out, int out_size, void* d_ws, size_t ws_size,
                              hipStream_t stream) {
    const void* node_features = d_in[0];
    const void* lattices      = d_in[1];
    const int* edge_index     = (const int*)d_in[2];
    const int* edge2graph     = (const int*)d_in[3];
    const void* frac_diff     = d_in[4];
    const void* W1e = d_in[5];  const void* b1e = d_in[6];
    const void* W2e = d_in[7];  const void* b2e = d_in[8];
    const void* W1n = d_in[9];  const void* b1n = d_in[10];
    const void* W2n = d_in[11]; const void* b2n = d_in[12];
    const void* ln_g = d_in[13];
    const void* ln_b = d_in[14];

    char* ws = (char*)d_ws;
    size_t off = 0;
    float* agg = (float*)(ws + off);            off += (size_t)N_NODES * H * 4;   // 51.2 MB (zeroed in prep)
    int*   cnt = (int*)(ws + off);              off += (size_t)N_NODES * 4;       // zeroed in zero_probe
    size_t cnt_zero_bytes = (size_t)N_NODES * 4;
    int*   flag = (int*)(ws + off);             off += 16;
    u16*   LGb  = (u16*)(ws + off);             off += (size_t)N_GRAPH * H * 2;   // 1.28 MB
    u16*   W1tp = (u16*)(ws + off);             off += (size_t)128 * 128 * 2;
    u16*   W1mp = (u16*)(ws + off);             off += (size_t)128 * 128 * 2;
    u16*   W2p  = (u16*)(ws + off);             off += (size_t)128 * 128 * 2;
    u16*   W1np = (u16*)(ws + off);             off += (size_t)256 * 128 * 2;
    u16*   W2np = (u16*)(ws + off);             off += (size_t)128 * 128 * 2;
    int*   starts = (int*)(ws + off);           off += (size_t)N_NODES * 4;
    int4*  rec  = (int4*)(ws + off);            off += (size_t)N_EDGE * 16;       // 16 MB

    // U, V live in d_out (dead until node_kernel writes it).
    u16* U = (u16*)d_out;
    u16* V = (u16*)d_out + (size_t)N_NODES * H;

    zero_probe_kernel<<<128, 256, 0, stream>>>((uint4*)cnt, (long)(cnt_zero_bytes / 16),
                                               (const unsigned*)node_features, flag);
    prep_kernel<<<PREP_TOTAL, 256, 0, stream>>>(W1e, W2e, W1n, W2n,
                                                W1tp, W1mp, W2p, W1np, W2np,
                                                lattices, b1e, LGb,
                                                edge_index, cnt, (uint4*)agg, flag);
    scan_kernel<<<NBLK, 256, 0, stream>>>(cnt, starts);
    sl_kernel<<<SL_TOTAL, 256, 0, stream>>>(edge_index, edge2graph, frac_diff, starts, rec,
                                            node_features, ln_g, ln_b,
                                            W1tp, W1mp, U, V, flag);
    edge_kernel<<<N_EDGE / 64, 256, 0, stream>>>(U, V, LGb, rec, W1e,
                                                 W2p, b2e, agg, flag);
    node_kernel<<<(N_NODES + 63) / 64, 256, 0, stream>>>(agg, cnt, node_features,
                                                         ln_g, ln_b,
                                                         W1np, W2np, b1n, b2n, d_out, flag);
}

// Round 13
// 398.022 us; speedup vs baseline: 1.0355x; 1.0355x over previous
//
#include <hip/hip_runtime.h>
#include <hip/hip_fp16.h>
#include <stdint.h>

// R20 = R19 resubmitted verbatim (Round 12 failed on infra: "MI355X container
// failed twice" -- no kernel signal). Structure = R17, best verified at
// 399.2us (R16 twin: 398.1us). Pipeline: zero_probe -> prep -> ps1 -> ps3 ->
// sl(scatter||lnuv) -> edge -> node.

#define N_NODES 100000
#define N_GRAPH 5000
#define N_EDGE  1000000
#define H 128
#define NBLK 391   // ceil(N_NODES/256)

typedef unsigned short u16;
typedef __attribute__((ext_vector_type(8))) short short8;
typedef __attribute__((ext_vector_type(4))) float floatx4;

__device__ inline float b2f(u16 x) {
    unsigned u = ((unsigned)x) << 16;
    return __uint_as_float(u);
}
__device__ inline u16 f2b(float f) {
    unsigned u = __float_as_uint(f);
    unsigned r = (u + 0x7FFFu + ((u >> 16) & 1u)) >> 16;  // RNE
    return (u16)r;
}
__device__ inline unsigned cvt_pk_bf16(float lo, float hi) {
    unsigned r;
    asm("v_cvt_pk_bf16_f32 %0, %1, %2" : "=v"(r) : "v"(lo), "v"(hi));
    return r;
}
__device__ inline float silu_f(float x) {
    float e = __builtin_amdgcn_exp2f(x * -1.442695040888963f);
    return x * __builtin_amdgcn_rcpf(1.f + e);
}
__device__ inline float get_bf(const uint4& v, int j) {
    unsigned w = ((const unsigned*)&v)[j >> 1];
    return b2f((u16)(w >> (16 * (j & 1))));
}
__device__ inline u16 f2h(float f) {       // f32 -> f16 bits (RNE, 1 op)
    return __half_as_ushort(__float2half(f));
}
__device__ inline __half2 h2u(unsigned w) {
    __half2 r; __builtin_memcpy(&r, &w, 4); return r;
}

// ---------------- zero workspace (agg+cnt) + dtype probe in one kernel ----------------
__global__ void zero_probe_kernel(uint4* __restrict__ zp, long n16,
                                  const unsigned* __restrict__ nf_raw, int* __restrict__ flag) {
    long i = (long)blockIdx.x * blockDim.x + threadIdx.x;
    long stride = (long)gridDim.x * blockDim.x;
    uint4 z = make_uint4(0, 0, 0, 0);
    for (; i < n16; i += stride) zp[i] = z;
    if (blockIdx.x == 0) {
        __shared__ int cnt_s;
        if (threadIdx.x == 0) cnt_s = 0;
        __syncthreads();
        unsigned u = nf_raw[threadIdx.x];
        unsigned e2 = (u >> 7) & 0xFF;
        atomicAdd(&cnt_s, (e2 >= 90 && e2 <= 160) ? 1 : 0);
        __syncthreads();
        if (threadIdx.x == 0) *flag = (cnt_s >= 128) ? 1 : 0;
    }
}

// ---------------- fused prep: packall (blk 0..47) + lg (48..1297) + cnt (1298..5204) ----------------
#define PREP_PACK_BLK 48
#define PREP_LG_BLK   1250
#define PREP_CNT_BLK  3907
#define PREP_TOTAL    (PREP_PACK_BLK + PREP_LG_BLK + PREP_CNT_BLK)

__global__ void prep_kernel(const void* __restrict__ W1e, const void* __restrict__ W2e,
                            const void* __restrict__ W1n, const void* __restrict__ W2n,
                            u16* __restrict__ W1tp, u16* __restrict__ W1mp, u16* __restrict__ W2p,
                            u16* __restrict__ W1np, u16* __restrict__ W2np,
                            const void* __restrict__ lat, const void* __restrict__ b1e,
                            u16* __restrict__ LGb,
                            const int* __restrict__ ei, int* __restrict__ cnt,
                            const int* __restrict__ flagp) {
    int blk = blockIdx.x;
    if (blk < PREP_PACK_BLK) {
        // ---- packall: 5 weight matrices -> MFMA B-fragment layout (bf16) ----
        int bf = *flagp;
        const void* W; u16* out; int k0, Ktot, base;
        if (blk < 8)       { W = W1e; out = W1tp; k0 = 0;   Ktot = 268; base = 0; }
        else if (blk < 16) { W = W1e; out = W1mp; k0 = 128; Ktot = 268; base = 8; }
        else if (blk < 24) { W = W2e; out = W2p;  k0 = 0;   Ktot = 128; base = 16; }
        else if (blk < 40) { W = W1n; out = W1np; k0 = 0;   Ktot = 256; base = 24; }
        else               { W = W2n; out = W2np; k0 = 0;   Ktot = 128; base = 40; }
        int t = (blk - base) * 256 + threadIdx.x;
        int lane = t & 63, nt = (t >> 6) & 7, kt = t >> 9;
        int n = nt * 16 + (lane & 15);
        int kbase = k0 + kt * 32 + ((lane >> 4) << 3);
        u16 vals[8];
        #pragma unroll
        for (int j = 0; j < 8; j++) {
            int k = kbase + j;
            if (k >= Ktot) vals[j] = 0;
            else if (bf) vals[j] = ((const u16*)W)[(size_t)k * H + n];
            else vals[j] = f2b(((const float*)W)[(size_t)k * H + n]);
        }
        uint4 tmp;
        __builtin_memcpy(&tmp, vals, 16);
        *(uint4*)(out + (size_t)t * 8) = tmp;
    } else if (blk < PREP_PACK_BLK + PREP_LG_BLK) {
        // ---- lg: LG[g][c] = b1e[c] + sum_ij ltl(g)_ij * W1e[256+ij][c]  (f16 out) ----
        int bf = *flagp;
        int t = (blk - PREP_PACK_BLK) * 256 + threadIdx.x;
        if (t >= N_GRAPH * 64) return;
        int g = t >> 6, cp = (t & 63) * 2;
        float L[9];
        #pragma unroll
        for (int k = 0; k < 9; k++)
            L[k] = bf ? b2f(((const u16*)lat)[g * 9 + k]) : ((const float*)lat)[g * 9 + k];
        float a0 = bf ? b2f(((const u16*)b1e)[cp])     : ((const float*)b1e)[cp];
        float a1 = bf ? b2f(((const u16*)b1e)[cp + 1]) : ((const float*)b1e)[cp + 1];
        #pragma unroll
        for (int i = 0; i < 3; i++) {
            #pragma unroll
            for (int j = 0; j < 3; j++) {
                float lt = L[i*3] * L[j*3] + L[i*3+1] * L[j*3+1] + L[i*3+2] * L[j*3+2];
                int r = 256 + i * 3 + j;
                float w0 = bf ? b2f(((const u16*)W1e)[(size_t)r * H + cp])     : ((const float*)W1e)[(size_t)r * H + cp];
                float w1 = bf ? b2f(((const u16*)W1e)[(size_t)r * H + cp + 1]) : ((const float*)W1e)[(size_t)r * H + cp + 1];
                a0 += lt * w0;
                a1 += lt * w1;
            }
        }
        LGb[(size_t)g * H + cp]     = f2h(a0);
        LGb[(size_t)g * H + cp + 1] = f2h(a1);
    } else {
        // ---- cnt: degree counts over edge_index[0] ----
        int e = (blk - PREP_PACK_BLK - PREP_LG_BLK) * 256 + threadIdx.x;
        if (e < N_EDGE) atomicAdd(&cnt[ei[e]], 1);
    }
}

// ---------------- prefix-scan of degrees -> starts (ps1, fused ps3) ----------------
__global__ void ps1_kernel(const int* __restrict__ cnt, int* __restrict__ bsum) {
    __shared__ int s[256];
    int i = blockIdx.x * 256 + threadIdx.x;
    s[threadIdx.x] = (i < N_NODES) ? cnt[i] : 0;
    __syncthreads();
    for (int off = 128; off >= 1; off >>= 1) {
        if (threadIdx.x < off) s[threadIdx.x] += s[threadIdx.x + off];
        __syncthreads();
    }
    if (threadIdx.x == 0) bsum[blockIdx.x] = s[0];
}

__global__ void ps3_kernel(const int* __restrict__ cnt, const int* __restrict__ bsum,
                           int* __restrict__ starts) {
    __shared__ int s[256];
    __shared__ int sOff;
    int b = blockIdx.x;
    int t = threadIdx.x;
    // block offset = sum of bsum[0..b-1] (b < 512; bsum has NBLK=391 entries)
    int v0 = (t < b) ? bsum[t] : 0;
    int v1 = (t + 256 < b) ? bsum[t + 256] : 0;
    s[t] = v0 + v1;
    __syncthreads();
    for (int off = 128; off >= 1; off >>= 1) {
        if (t < off) s[t] += s[t + off];
        __syncthreads();
    }
    if (t == 0) sOff = s[0];
    __syncthreads();
    // local inclusive scan of cnt within this block
    int i = b * 256 + t;
    int v = (i < N_NODES) ? cnt[i] : 0;
    s[t] = v;
    __syncthreads();
    for (int off = 1; off < 256; off <<= 1) {
        int add = (t >= off) ? s[t - off] : 0;
        __syncthreads();
        s[t] += add;
        __syncthreads();
    }
    if (i < N_NODES) starts[i] = sOff + s[t] - v;
}

// ---------------- fused scatter + lnuv (independent producers for edge) ----------------
#define UVP 136
#define SC_BLK 3907                 // ceil(N_EDGE/256)
#define LN_BLK 1563                 // ceil(N_NODES/64)
#define SL_TOTAL (SC_BLK + LN_BLK)  // 5470

__global__ __launch_bounds__(256, 3) void sl_kernel(
    // scatter args
    const int* __restrict__ ei, const int* __restrict__ e2g,
    const void* __restrict__ fd, int* __restrict__ starts, int4* __restrict__ rec,
    // lnuv args
    const void* __restrict__ nf, const void* __restrict__ lng, const void* __restrict__ lnb,
    const u16* __restrict__ Wtp, const u16* __restrict__ Wmp,
    u16* __restrict__ U, u16* __restrict__ V,
    const int* __restrict__ flagp) {
    __shared__ __align__(16) u16 sA[64 * UVP];
    int blk = blockIdx.x;
    int tid = threadIdx.x;
    int bf = *flagp;

    // Bresenham role split: lnuv iff floor((blk+1)*LN/TOT) > floor(blk*LN/TOT)
    int li = (int)(((long)blk * LN_BLK) / SL_TOTAL);
    int isLn = (int)(((long)(blk + 1) * LN_BLK) / SL_TOTAL) > li;

    if (!isLn) {
        // ================= scatter body =================
        int si = blk - li;
        int e = si * 256 + tid;
        if (e >= N_EDGE) return;
        int s = ei[e];
        int pos = atomicAdd(&starts[s], 1);
        float f0, f1, f2v;
        if (bf) {
            const u16* f = (const u16*)fd + (size_t)e * 3;
            f0 = b2f(f[0]); f1 = b2f(f[1]); f2v = b2f(f[2]);
        } else {
            const float* f = (const float*)fd + (size_t)e * 3;
            f0 = f[0]; f1 = f[1]; f2v = f[2];
        }
        int fd01 = (int)((unsigned)f2h(f0) | ((unsigned)f2h(f1) << 16));
        int gz = (int)((unsigned)e2g[e] | ((unsigned)f2h(f2v) << 16));
        rec[pos] = make_int4(s, ei[N_EDGE + e], gz, fd01);
        return;
    }

    // ================= lnuv body (no h store) =================
    int lane = tid & 63, w = tid >> 6;
    int r0 = li * 64;

    {
        int row = tid >> 2, part = tid & 3;
        int gr = r0 + row;
        int grc = (gr < N_NODES) ? gr : N_NODES - 1;
        float x[32];
        if (bf) {
            const u16* p = (const u16*)nf + (size_t)grc * H + part * 32;
            #pragma unroll
            for (int j8 = 0; j8 < 4; j8++) {
                uint4 v = *(const uint4*)(p + j8 * 8);
                #pragma unroll
                for (int j = 0; j < 8; j++) x[j8 * 8 + j] = get_bf(v, j);
            }
        } else {
            const float* p = (const float*)nf + (size_t)grc * H + part * 32;
            #pragma unroll
            for (int j4 = 0; j4 < 8; j4++) {
                float4 v = *(const float4*)(p + j4 * 4);
                x[j4*4] = v.x; x[j4*4+1] = v.y; x[j4*4+2] = v.z; x[j4*4+3] = v.w;
            }
        }
        float s1 = 0.f, s2 = 0.f;
        #pragma unroll
        for (int j = 0; j < 32; j++) { s1 += x[j]; s2 += x[j] * x[j]; }
        s1 += __shfl_xor(s1, 1, 64); s2 += __shfl_xor(s2, 1, 64);
        s1 += __shfl_xor(s1, 2, 64); s2 += __shfl_xor(s2, 2, 64);
        float mu = s1 * (1.0f / H);
        float var = s2 * (1.0f / H) - mu * mu;
        float rs = rsqrtf(var + 1e-5f);
        unsigned pk[16];
        if (bf) {
            const u16* gp = (const u16*)lng + part * 32;
            const u16* bp = (const u16*)lnb + part * 32;
            #pragma unroll
            for (int j8 = 0; j8 < 4; j8++) {
                uint4 gv = *(const uint4*)(gp + j8 * 8);
                uint4 bv = *(const uint4*)(bp + j8 * 8);
                #pragma unroll
                for (int j2 = 0; j2 < 4; j2++) {
                    int j = j8 * 8 + j2 * 2;
                    float y0 = (x[j] - mu) * rs * get_bf(gv, j2*2)     + get_bf(bv, j2*2);
                    float y1 = (x[j+1] - mu) * rs * get_bf(gv, j2*2+1) + get_bf(bv, j2*2+1);
                    pk[j >> 1] = cvt_pk_bf16(y0, y1);
                }
            }
        } else {
            const float* gp = (const float*)lng + part * 32;
            const float* bp = (const float*)lnb + part * 32;
            #pragma unroll
            for (int j4 = 0; j4 < 8; j4++) {
                float4 gv = *(const float4*)(gp + j4 * 4);
                float4 bv = *(const float4*)(bp + j4 * 4);
                int j = j4 * 4;
                float y0 = (x[j]   - mu) * rs * gv.x + bv.x;
                float y1 = (x[j+1] - mu) * rs * gv.y + bv.y;
                float y2 = (x[j+2] - mu) * rs * gv.z + bv.z;
                float y3 = (x[j+3] - mu) * rs * gv.w + bv.w;
                pk[j >> 1]       = cvt_pk_bf16(y0, y1);
                pk[(j >> 1) + 1] = cvt_pk_bf16(y2, y3);
            }
        }
        uint4* d = (uint4*)&sA[row * UVP + part * 32];
        #pragma unroll
        for (int j4 = 0; j4 < 4; j4++)
            d[j4] = make_uint4(pk[j4*4], pk[j4*4+1], pk[j4*4+2], pk[j4*4+3]);
    }
    __syncthreads();

    const short8* Wt = (const short8*)Wtp;
    const short8* Wm = (const short8*)Wmp;
    int q8 = (lane >> 4) * 8;
    int mrow = lane & 15;
    int q = lane >> 4;

    floatx4 aU[4][2], aV[4][2];
    #pragma unroll
    for (int mt = 0; mt < 4; mt++) {
        aU[mt][0] = (floatx4){0,0,0,0}; aU[mt][1] = (floatx4){0,0,0,0};
        aV[mt][0] = (floatx4){0,0,0,0}; aV[mt][1] = (floatx4){0,0,0,0};
    }
    #pragma unroll
    for (int kt = 0; kt < 4; kt++) {
        short8 bu0 = Wt[(kt * 8 + 2 * w) * 64 + lane];
        short8 bu1 = Wt[(kt * 8 + 2 * w + 1) * 64 + lane];
        short8 bv0 = Wm[(kt * 8 + 2 * w) * 64 + lane];
        short8 bv1 = Wm[(kt * 8 + 2 * w + 1) * 64 + lane];
        #pragma unroll
        for (int mt = 0; mt < 4; mt++) {
            short8 a = *(const short8*)(&sA[(mt * 16 + mrow) * UVP + kt * 32 + q8]);
            aU[mt][0] = __builtin_amdgcn_mfma_f32_16x16x32_bf16(a, bu0, aU[mt][0], 0, 0, 0);
            aU[mt][1] = __builtin_amdgcn_mfma_f32_16x16x32_bf16(a, bu1, aU[mt][1], 0, 0, 0);
            aV[mt][0] = __builtin_amdgcn_mfma_f32_16x16x32_bf16(a, bv0, aV[mt][0], 0, 0, 0);
            aV[mt][1] = __builtin_amdgcn_mfma_f32_16x16x32_bf16(a, bv1, aV[mt][1], 0, 0, 0);
        }
    }
    __syncthreads();   // sA free; LDS-bounce U then V for vector stores (f16)

    #pragma unroll
    for (int mt = 0; mt < 4; mt++)
        #pragma unroll
        for (int nt = 0; nt < 2; nt++) {
            int n = w * 32 + nt * 16 + mrow;
            #pragma unroll
            for (int r = 0; r < 4; r++)
                sA[(mt * 16 + q * 4 + r) * UVP + n] = f2h(aU[mt][nt][r]);
        }
    __syncthreads();
    for (int i = tid; i < 1024; i += 256) {
        int row = i >> 4, c = i & 15;
        int gr = r0 + row;
        if (gr < N_NODES)
            *(uint4*)(U + (size_t)gr * H + c * 8) = *(const uint4*)(&sA[row * UVP + c * 8]);
    }
    __syncthreads();
    #pragma unroll
    for (int mt = 0; mt < 4; mt++)
        #pragma unroll
        for (int nt = 0; nt < 2; nt++) {
            int n = w * 32 + nt * 16 + mrow;
            #pragma unroll
            for (int r = 0; r < 4; r++)
                sA[(mt * 16 + q * 4 + r) * UVP + n] = f2h(aV[mt][nt][r]);
        }
    __syncthreads();
    for (int i = tid; i < 1024; i += 256) {
        int row = i >> 4, c = i & 15;
        int gr = r0 + row;
        if (gr < N_NODES)
            *(uint4*)(V + (size_t)gr * H + c * 8) = *(const uint4*)(&sA[row * UVP + c * 8]);
    }
}

// ---------------- fused edge (src-sorted): packed-f16 gather + silu -> layer2 GEMM -> segmented reduce ----------------
#define PP 136   // bf16 stage-1 stride (u16 units)
#define PF2 132  // f32 chunked-epilogue stride (floats); 132%32=4 -> 2-way banks

__global__ __launch_bounds__(256, 8) void edge_kernel(
    const u16* __restrict__ U, const u16* __restrict__ V, const u16* __restrict__ LGb,
    const int4* __restrict__ rec,
    const void* __restrict__ W1e,
    const u16* __restrict__ W2p, const void* __restrict__ bias2,
    float* __restrict__ agg, const int* __restrict__ flagp) {
    __shared__ __align__(16) u16 sP[64 * PP];
    float* sPf = (float*)sP;
    __shared__ int sSrc[64], sDst[64], sG[64];
    __shared__ unsigned sFdU[192];   // f16x2 splats: {f0,f0},{f1,f1},{f2,f2} per row
    __shared__ float sB2[128];

    int bf = *flagp;
    int tid = threadIdx.x;
    int lane = tid & 63, w = tid >> 6;
    int e0 = blockIdx.x * 64;

    if (tid < 64) {
        int4 r = rec[e0 + tid];
        sSrc[tid] = r.x; sDst[tid] = r.y;
        sG[tid] = (int)((unsigned)r.z & 0xFFFFu);
        unsigned wv = (unsigned)r.w;
        unsigned a = wv & 0xFFFFu;
        unsigned b = wv >> 16;
        unsigned c = ((unsigned)r.z) >> 16;
        sFdU[tid * 3 + 0] = a | (a << 16);
        sFdU[tid * 3 + 1] = b | (b << 16);
        sFdU[tid * 3 + 2] = c | (c << 16);
    }
    if (tid < 128) sB2[tid] = bf ? b2f(((const u16*)bias2)[tid]) : ((const float*)bias2)[tid];

    // Wfd = W1e rows 265..267, cols c8..c8+7 (fixed per thread) -> f16x2 pairs
    int c8 = (tid & 15) * 8;
    __half2 wfh[3][4];
    if (bf) {
        #pragma unroll
        for (int k = 0; k < 3; k++) {
            uint4 wv = *(const uint4*)((const u16*)W1e + (size_t)(265 + k) * H + c8);
            #pragma unroll
            for (int jj = 0; jj < 4; jj++)
                wfh[k][jj] = __floats2half2_rn(get_bf(wv, 2 * jj), get_bf(wv, 2 * jj + 1));
        }
    } else {
        #pragma unroll
        for (int k = 0; k < 3; k++) {
            const float* wr = (const float*)W1e + (size_t)(265 + k) * H + c8;
            float4 a4 = *(const float4*)wr;
            float4 b4 = *(const float4*)(wr + 4);
            wfh[k][0] = __floats2half2_rn(a4.x, a4.y);
            wfh[k][1] = __floats2half2_rn(a4.z, a4.w);
            wfh[k][2] = __floats2half2_rn(b4.x, b4.y);
            wfh[k][3] = __floats2half2_rn(b4.z, b4.w);
        }
    }
    __syncthreads();

    // gather: packed f16 adds/fmas -> f32 silu -> bf16 A-tile in sP
    for (int i = tid; i < 1024; i += 256) {
        int row = i >> 4;
        int s = sSrc[row], d = sDst[row], g = sG[row];
        uint4 uu = *(const uint4*)(U + (size_t)s * H + c8);
        uint4 vv = *(const uint4*)(V + (size_t)d * H + c8);
        uint4 gg = *(const uint4*)(LGb + (size_t)g * H + c8);
        __half2 f0h = h2u(sFdU[row * 3 + 0]);
        __half2 f1h = h2u(sFdU[row * 3 + 1]);
        __half2 f2h = h2u(sFdU[row * 3 + 2]);
        float y[8];
        #pragma unroll
        for (int jj = 0; jj < 4; jj++) {
            __half2 z = __hadd2(h2u(((const unsigned*)&uu)[jj]), h2u(((const unsigned*)&vv)[jj]));
            z = __hadd2(z, h2u(((const unsigned*)&gg)[jj]));
            z = __hfma2(f0h, wfh[0][jj], z);
            z = __hfma2(f1h, wfh[1][jj], z);
            z = __hfma2(f2h, wfh[2][jj], z);
            float2 zf = __half22float2(z);
            y[2 * jj]     = silu_f(zf.x);
            y[2 * jj + 1] = silu_f(zf.y);
        }
        uint4 packed = make_uint4(cvt_pk_bf16(y[0], y[1]), cvt_pk_bf16(y[2], y[3]),
                                  cvt_pk_bf16(y[4], y[5]), cvt_pk_bf16(y[6], y[7]));
        *(uint4*)(&sP[row * PP + c8]) = packed;
    }
    __syncthreads();

    const short8* W2v = (const short8*)W2p;
    int q8 = (lane >> 4) * 8;
    int mrow = lane & 15;
    int q = lane >> 4;

    // layer 2: [64,128] @ [128,128]
    floatx4 acc2[4][2];
    #pragma unroll
    for (int mt = 0; mt < 4; mt++) {
        acc2[mt][0] = (floatx4){0,0,0,0};
        acc2[mt][1] = (floatx4){0,0,0,0};
    }
    #pragma unroll
    for (int kt = 0; kt < 4; kt++) {
        short8 bf0 = W2v[(kt * 8 + 2 * w) * 64 + lane];
        short8 bf1 = W2v[(kt * 8 + 2 * w + 1) * 64 + lane];
        #pragma unroll
        for (int mt = 0; mt < 4; mt++) {
            short8 a = *(const short8*)(&sP[(mt * 16 + mrow) * PP + kt * 32 + q8]);
            acc2[mt][0] = __builtin_amdgcn_mfma_f32_16x16x32_bf16(a, bf0, acc2[mt][0], 0, 0, 0);
            acc2[mt][1] = __builtin_amdgcn_mfma_f32_16x16x32_bf16(a, bf1, acc2[mt][1], 0, 0, 0);
        }
    }
    __syncthreads();   // all sP A-frag reads done; safe to overwrite with f32 chunk

    // bias + silu -> f32 LDS in two 32-row chunks (mt 0,1 then mt 2,3),
    // each followed by the segmented reduce over that chunk.
    int col = tid & 127;
    int sub = tid >> 7;
    #pragma unroll
    for (int ch = 0; ch < 2; ch++) {
        if (ch) __syncthreads();     // chunk-0 reduce reads done before overwrite
        #pragma unroll
        for (int mt2 = 0; mt2 < 2; mt2++) {
            int mt = ch * 2 + mt2;
            #pragma unroll
            for (int nt = 0; nt < 2; nt++) {
                int n = w * 32 + nt * 16 + mrow;
                float bias = sB2[n];
                #pragma unroll
                for (int r = 0; r < 4; r++) {
                    int rl = mt2 * 16 + q * 4 + r;   // chunk-local row
                    sPf[rl * PF2 + n] = silu_f(acc2[mt][nt][r] + bias);
                }
            }
        }
        __syncthreads();
        // segmented reduce: 16-row window per thread-half, one atomic per run
        int rbase = sub * 16;                 // chunk-local
        int growb = ch * 32 + rbase;          // block-local (for sSrc)
        float acc = 0.f;
        int cur = sSrc[growb];
        #pragma unroll 4
        for (int rr = 0; rr < 16; rr++) {
            int s = sSrc[growb + rr];
            if (s != cur) {
                atomicAdd(&agg[(size_t)cur * H + col], acc);
                acc = 0.f;
                cur = s;
            }
            acc += sPf[(rbase + rr) * PF2 + col];
        }
        atomicAdd(&agg[(size_t)cur * H + col], acc);
    }
}

// ---------------- node MLP + residual (LN recomputed from nf; h array deleted) ----------------
#define NKP 264

__global__ __launch_bounds__(256, 4) void node_kernel(
    const float* __restrict__ agg, const int* __restrict__ cnt,
    const void* __restrict__ nf,
    const void* __restrict__ lng, const void* __restrict__ lnb,
    const u16* __restrict__ W1p, const u16* __restrict__ W2p,
    const void* __restrict__ bias1, const void* __restrict__ bias2,
    void* __restrict__ out, const int* __restrict__ flagp) {
    __shared__ __align__(16) u16 sU[64 * NKP];
    __shared__ float sB1[128], sB2[128];
    u16* sA = sU;
    u16* sP = sU;

    int bf = *flagp;
    int tid = threadIdx.x;
    int lane = tid & 63, w = tid >> 6;
    int r0 = blockIdx.x * 64;

    if (tid < 128) sB1[tid] = bf ? b2f(((const u16*)bias1)[tid]) : ((const float*)bias1)[tid];
    else sB2[tid - 128] = bf ? b2f(((const u16*)bias2)[tid - 128]) : ((const float*)bias2)[tid - 128];

    // ---- LN stage (identical math to lnuv -> bit-identical bf16): cols 0..127 ----
    {
        int row = tid >> 2, part = tid & 3;
        int gr = r0 + row;
        int grc = (gr < N_NODES) ? gr : N_NODES - 1;
        float x[32];
        if (bf) {
            const u16* p = (const u16*)nf + (size_t)grc * H + part * 32;
            #pragma unroll
            for (int j8 = 0; j8 < 4; j8++) {
                uint4 v = *(const uint4*)(p + j8 * 8);
                #pragma unroll
                for (int j = 0; j < 8; j++) x[j8 * 8 + j] = get_bf(v, j);
            }
        } else {
            const float* p = (const float*)nf + (size_t)grc * H + part * 32;
            #pragma unroll
            for (int j4 = 0; j4 < 8; j4++) {
                float4 v = *(const float4*)(p + j4 * 4);
                x[j4*4] = v.x; x[j4*4+1] = v.y; x[j4*4+2] = v.z; x[j4*4+3] = v.w;
            }
        }
        float s1 = 0.f, s2 = 0.f;
        #pragma unroll
        for (int j = 0; j < 32; j++) { s1 += x[j]; s2 += x[j] * x[j]; }
        s1 += __shfl_xor(s1, 1, 64); s2 += __shfl_xor(s2, 1, 64);
        s1 += __shfl_xor(s1, 2, 64); s2 += __shfl_xor(s2, 2, 64);
        float mu = s1 * (1.0f / H);
        float var = s2 * (1.0f / H) - mu * mu;
        float rs = rsqrtf(var + 1e-5f);
        unsigned pk[16];
        if (bf) {
            const u16* gp = (const u16*)lng + part * 32;
            const u16* bp = (const u16*)lnb + part * 32;
            #pragma unroll
            for (int j8 = 0; j8 < 4; j8++) {
                uint4 gv = *(const uint4*)(gp + j8 * 8);
                uint4 bv = *(const uint4*)(bp + j8 * 8);
                #pragma unroll
                for (int j2 = 0; j2 < 4; j2++) {
                    int j = j8 * 8 + j2 * 2;
                    float y0 = (x[j] - mu) * rs * get_bf(gv, j2*2)     + get_bf(bv, j2*2);
                    float y1 = (x[j+1] - mu) * rs * get_bf(gv, j2*2+1) + get_bf(bv, j2*2+1);
                    pk[j >> 1] = cvt_pk_bf16(y0, y1);
                }
            }
        } else {
            const float* gp = (const float*)lng + part * 32;
            const float* bp = (const float*)lnb + part * 32;
            #pragma unroll
            for (int j4 = 0; j4 < 8; j4++) {
                float4 gv = *(const float4*)(gp + j4 * 4);
                float4 bv = *(const float4*)(bp + j4 * 4);
                int j = j4 * 4;
                float y0 = (x[j]   - mu) * rs * gv.x + bv.x;
                float y1 = (x[j+1] - mu) * rs * gv.y + bv.y;
                float y2 = (x[j+2] - mu) * rs * gv.z + bv.z;
                float y3 = (x[j+3] - mu) * rs * gv.w + bv.w;
                pk[j >> 1]       = cvt_pk_bf16(y0, y1);
                pk[(j >> 1) + 1] = cvt_pk_bf16(y2, y3);
            }
        }
        uint4* d = (uint4*)&sA[row * NKP + part * 32];
        #pragma unroll
        for (int j4 = 0; j4 < 4; j4++)
            d[j4] = make_uint4(pk[j4*4], pk[j4*4+1], pk[j4*4+2], pk[j4*4+3]);
    }

    // stage agg/cnt rows (cols 128..255), fp32 -> bf16 with packed converts
    for (int i = tid; i < 1024; i += 256) {
        int row = i >> 4, c = i & 15;
        int gr = r0 + row; if (gr >= N_NODES) gr = N_NODES - 1;
        int cn = cnt[gr];
        float sc = 1.0f / (float)(cn > 0 ? cn : 1);
        const float* ap = agg + (size_t)gr * H + c * 8;
        float4 a4 = *(const float4*)ap;
        float4 b4 = *(const float4*)(ap + 4);
        uint4 packed = make_uint4(cvt_pk_bf16(a4.x * sc, a4.y * sc), cvt_pk_bf16(a4.z * sc, a4.w * sc),
                                  cvt_pk_bf16(b4.x * sc, b4.y * sc), cvt_pk_bf16(b4.z * sc, b4.w * sc));
        *(uint4*)(&sA[row * NKP + 128 + c * 8]) = packed;
    }
    __syncthreads();

    const short8* W1v = (const short8*)W1p;
    const short8* W2v = (const short8*)W2p;
    int q8 = (lane >> 4) * 8;
    int mrow = lane & 15;
    int q = lane >> 4;

    floatx4 acc[4][2];
    #pragma unroll
    for (int mt = 0; mt < 4; mt++) {
        acc[mt][0] = (floatx4){0,0,0,0};
        acc[mt][1] = (floatx4){0,0,0,0};
    }
    #pragma unroll
    for (int kt = 0; kt < 8; kt++) {
        short8 bf0 = W1v[(kt * 8 + 2 * w) * 64 + lane];
        short8 bf1 = W1v[(kt * 8 + 2 * w + 1) * 64 + lane];
        #pragma unroll
        for (int mt = 0; mt < 4; mt++) {
            short8 a = *(const short8*)(&sA[(mt * 16 + mrow) * NKP + kt * 32 + q8]);
            acc[mt][0] = __builtin_amdgcn_mfma_f32_16x16x32_bf16(a, bf0, acc[mt][0], 0, 0, 0);
            acc[mt][1] = __builtin_amdgcn_mfma_f32_16x16x32_bf16(a, bf1, acc[mt][1], 0, 0, 0);
        }
    }
    __syncthreads();

    #pragma unroll
    for (int mt = 0; mt < 4; mt++) {
        #pragma unroll
        for (int nt = 0; nt < 2; nt++) {
            int n = w * 32 + nt * 16 + mrow;
            float bias = sB1[n];
            #pragma unroll
            for (int r = 0; r < 4; r++) {
                int row = mt * 16 + q * 4 + r;
                sP[row * PP + n] = f2b(silu_f(acc[mt][nt][r] + bias));
            }
        }
    }
    __syncthreads();

    floatx4 acc2[4][2];
    #pragma unroll
    for (int mt = 0; mt < 4; mt++) {
        acc2[mt][0] = (floatx4){0,0,0,0};
        acc2[mt][1] = (floatx4){0,0,0,0};
    }
    #pragma unroll
    for (int kt = 0; kt < 4; kt++) {
        short8 bf0 = W2v[(kt * 8 + 2 * w) * 64 + lane];
        short8 bf1 = W2v[(kt * 8 + 2 * w + 1) * 64 + lane];
        #pragma unroll
        for (int mt = 0; mt < 4; mt++) {
            short8 a = *(const short8*)(&sP[(mt * 16 + mrow) * PP + kt * 32 + q8]);
            acc2[mt][0] = __builtin_amdgcn_mfma_f32_16x16x32_bf16(a, bf0, acc2[mt][0], 0, 0, 0);
            acc2[mt][1] = __builtin_amdgcn_mfma_f32_16x16x32_bf16(a, bf1, acc2[mt][1], 0, 0, 0);
        }
    }
    __syncthreads();   // sP free again; LDS-bounce for vector out stores

    #pragma unroll
    for (int mt = 0; mt < 4; mt++) {
        #pragma unroll
        for (int nt = 0; nt < 2; nt++) {
            int n = w * 32 + nt * 16 + mrow;
            float bias = sB2[n];
            #pragma unroll
            for (int r = 0; r < 4; r++) {
                int row = mt * 16 + q * 4 + r;
                sP[row * PP + n] = f2b(silu_f(acc2[mt][nt][r] + bias));
            }
        }
    }
    __syncthreads();

    // vectorized residual add + store
    for (int i = tid; i < 1024; i += 256) {
        int row = i >> 4, c = i & 15;
        int gr = r0 + row;
        if (gr >= N_NODES) continue;
        uint4 sv = *(const uint4*)(&sP[row * PP + c * 8]);
        size_t idx = (size_t)gr * H + c * 8;
        if (bf) {
            uint4 nv = *(const uint4*)((const u16*)nf + idx);
            float o[8];
            #pragma unroll
            for (int j = 0; j < 8; j++) o[j] = get_bf(nv, j) + get_bf(sv, j);
            uint4 packed = make_uint4(cvt_pk_bf16(o[0], o[1]), cvt_pk_bf16(o[2], o[3]),
                                      cvt_pk_bf16(o[4], o[5]), cvt_pk_bf16(o[6], o[7]));
            *(uint4*)((u16*)out + idx) = packed;
        } else {
            const float* np = (const float*)nf + idx;
            float4 a4 = *(const float4*)np;
            float4 b4 = *(const float4*)(np + 4);
            a4.x += get_bf(sv, 0); a4.y += get_bf(sv, 1); a4.z += get_bf(sv, 2); a4.w += get_bf(sv, 3);
            b4.x += get_bf(sv, 4); b4.y += get_bf(sv, 5); b4.z += get_bf(sv, 6); b4.w += get_bf(sv, 7);
            float* op = (float*)out + idx;
            *(float4*)op = a4;
            *(float4*)(op + 4) = b4;
        }
    }
}

extern "C" void kernel_launch(void* const* d_in, const int* in_sizes, int n_in,
                              void* d_out, int out_size, void* d_ws, size_t ws_size,
                              hipStream_t stream) {
    const void* node_features = d_in[0];
    const void* lattices      = d_in[1];
    const int* edge_index     = (const int*)d_in[2];
    const int* edge2graph     = (const int*)d_in[3];
    const void* frac_diff     = d_in[4];
    const void* W1e = d_in[5];  const void* b1e = d_in[6];
    const void* W2e = d_in[7];  const void* b2e = d_in[8];
    const void* W1n = d_in[9];  const void* b1n = d_in[10];
    const void* W2n = d_in[11]; const void* b2n = d_in[12];
    const void* ln_g = d_in[13];
    const void* ln_b = d_in[14];

    char* ws = (char*)d_ws;
    size_t off = 0;
    float* agg = (float*)(ws + off);            off += (size_t)N_NODES * H * 4;   // 51.2 MB
    int*   cnt = (int*)(ws + off);              off += (size_t)N_NODES * 4;
    size_t zero_bytes = off;                    // agg + cnt (multiple of 16)
    int*   flag = (int*)(ws + off);             off += 16;
    u16*   LGb  = (u16*)(ws + off);             off += (size_t)N_GRAPH * H * 2;   // 1.28 MB
    u16*   W1tp = (u16*)(ws + off);             off += (size_t)128 * 128 * 2;
    u16*   W1mp = (u16*)(ws + off);             off += (size_t)128 * 128 * 2;
    u16*   W2p  = (u16*)(ws + off);             off += (size_t)128 * 128 * 2;
    u16*   W1np = (u16*)(ws + off);             off += (size_t)256 * 128 * 2;
    u16*   W2np = (u16*)(ws + off);             off += (size_t)128 * 128 * 2;
    int*   starts = (int*)(ws + off);           off += (size_t)N_NODES * 4;
    int*   bsum = (int*)(ws + off);             off += 2048;
    int4*  rec  = (int4*)(ws + off);            off += (size_t)N_EDGE * 16;       // 16 MB

    // U, V live in d_out (dead until node_kernel writes it).
    u16* U = (u16*)d_out;
    u16* V = (u16*)d_out + (size_t)N_NODES * H;

    zero_probe_kernel<<<2048, 256, 0, stream>>>((uint4*)ws, (long)(zero_bytes / 16),
                                                (const unsigned*)node_features, flag);
    prep_kernel<<<PREP_TOTAL, 256, 0, stream>>>(W1e, W2e, W1n, W2n,
                                                W1tp, W1mp, W2p, W1np, W2np,
                                                lattices, b1e, LGb,
                                                edge_index, cnt, flag);
    ps1_kernel<<<NBLK, 256, 0, stream>>>(cnt, bsum);
    ps3_kernel<<<NBLK, 256, 0, stream>>>(cnt, bsum, starts);
    sl_kernel<<<SL_TOTAL, 256, 0, stream>>>(edge_index, edge2graph, frac_diff, starts, rec,
                                            node_features, ln_g, ln_b,
                                            W1tp, W1mp, U, V, flag);
    edge_kernel<<<N_EDGE / 64, 256, 0, stream>>>(U, V, LGb, rec, W1e,
                                                 W2p, b2e, agg, flag);
    node_kernel<<<(N_NODES + 63) / 64, 256, 0, stream>>>(agg, cnt, node_features,
                                                         ln_g, ln_b,
                                                         W1np, W2np, b1n, b2n, d_out, flag);
}